// Round 4
// baseline (136.031 us; speedup 1.0000x reference)
//
#include <hip/hip_runtime.h>
#include <hip/hip_bf16.h>
#include <math.h>

// B=4, T=128, S=512, D=512. Outputs: attn_h (4,128,512) then align (4,128,512), fp32.
// 3-kernel pipeline (R9 = R7's K1/K2 + softmax folded into K4, no atomics):
//   K1 fused_front (640): Ew=exp(2(inp@Wq^T+bq)), Eu=exp(2 ctx@Wc^T),
//      GT[b]=(WL@ctx_b^T) bf16, Y0=inp@WR^T+bout
//   K2 align (2048): E[b,t,s] = exp(V - 2*sum_d v[d]/(1+Ew*Eu)) (= exp(sum v*tanh))
//      paired rcp; |S|<=sum|v|~18 so exp is fp32-safe without max-subtract.
//   K3 gemm_att_sm (64): per-block local rowsum of E -> rinv (LDS, no atomics);
//      attn = (E*rinv)_bf16 @ GT^T + Y0 (MFMA); y==0 blocks write alignv=E*rinv.

typedef __attribute__((ext_vector_type(8))) short short8;
typedef __attribute__((ext_vector_type(4))) float f32x4;
typedef unsigned short ushort_t;

static __device__ __forceinline__ unsigned short f2bf(float x) {
    union { __hip_bfloat16 h; unsigned short u; } c;
    c.h = __float2bfloat16(x);
    return c.u;
}
static __device__ __forceinline__ int bf2x(float lo, float hi) {
    return (int)(((unsigned)f2bf(hi) << 16) | (unsigned)f2bf(lo));
}

template<bool BF>
static __device__ __forceinline__ void load16(const void* base, size_t elemoff,
                                              int4& r0, int4& r1) {
    if (BF) {
        const int4* p = (const int4*)((const ushort_t*)base + elemoff);
        r0 = p[0]; r1 = p[1];
    } else {
        const float4* p = (const float4*)((const float*)base + elemoff);
        float4 a = p[0], b = p[1], c = p[2], d = p[3];
        r0.x = bf2x(a.x, a.y); r0.y = bf2x(a.z, a.w);
        r0.z = bf2x(b.x, b.y); r0.w = bf2x(b.z, b.w);
        r1.x = bf2x(c.x, c.y); r1.y = bf2x(c.z, c.w);
        r1.z = bf2x(d.x, d.y); r1.w = bf2x(d.z, d.w);
    }
}

// fp32 load + per-row scale + bf16 pack (for P = E * rinv staging)
static __device__ __forceinline__ void load16s(const void* base, size_t elemoff,
                                               float s, int4& r0, int4& r1) {
    const float4* p = (const float4*)((const float*)base + elemoff);
    float4 a = p[0], b = p[1], c = p[2], d = p[3];
    a.x *= s; a.y *= s; a.z *= s; a.w *= s;
    b.x *= s; b.y *= s; b.z *= s; b.w *= s;
    c.x *= s; c.y *= s; c.z *= s; c.w *= s;
    d.x *= s; d.y *= s; d.z *= s; d.w *= s;
    r0.x = bf2x(a.x, a.y); r0.y = bf2x(a.z, a.w);
    r0.z = bf2x(b.x, b.y); r0.w = bf2x(b.z, b.w);
    r1.x = bf2x(c.x, c.y); r1.y = bf2x(c.z, c.w);
    r1.z = bf2x(d.x, d.y); r1.w = bf2x(d.z, d.w);
}

// ---------------------------------------------------------------------------
// MFMA NT GEMM tile: C[m,n] = sum_k A[m,k]*W[n,k] (+bias). 64x64 tile, BK=64,
// 256 thr = 4 waves (2x2 of 32x32), 2x2 MFMA 16x16x32 per 32-K step.
// LDS rows padded to 72 bf16 (<=2-way bank aliasing on b128 = free).
// EPI: 0 fp32+bias; 1 fp32 exp(2*(x+bias)); 2 bf16; 3 fp32 + partial[].
// A_SCALE: A is fp32 scaled per-row by ascale[srow] before bf16 pack.
// ---------------------------------------------------------------------------
template<bool A_BF, bool W_BF, int EPI, bool A_SCALE = false>
static __device__ __forceinline__ void gemm_body(
    ushort_t* As, ushort_t* Ws,
    const void* A, const void* W, const float* bias, const float* partial,
    void* Cv, int K, int lda, int ldw, int ldc, int bm, int bn,
    const float* ascale = nullptr)
{
    const int tid = threadIdx.x;
    const int wave = tid >> 6, lane = tid & 63;
    const int mh = (wave & 1) * 32, nh = (wave >> 1) * 32;
    const int quad = lane >> 4, l16 = lane & 15;
    const int srow = tid >> 2, schunk = tid & 3;

    const size_t aoff = (size_t)(bm + srow) * lda + schunk * 16;
    const size_t woff = (size_t)(bn + srow) * ldw + schunk * 16;
    int4* AsW = (int4*)&As[srow * 72 + schunk * 16];
    int4* WsW = (int4*)&Ws[srow * 72 + schunk * 16];

    const float asc = A_SCALE ? ascale[srow] : 1.f;

    f32x4 acc00 = {0.f, 0.f, 0.f, 0.f}, acc01 = acc00, acc10 = acc00, acc11 = acc00;

    int4 a0r, a1r, w0r, w1r;
    if (A_SCALE) load16s(A, aoff, asc, a0r, a1r);
    else         load16<A_BF>(A, aoff, a0r, a1r);
    load16<W_BF>(W, woff, w0r, w1r);

    for (int k0 = 0; k0 < K; k0 += 64) {
        AsW[0] = a0r; AsW[1] = a1r;
        WsW[0] = w0r; WsW[1] = w1r;
        __syncthreads();
        if (k0 + 64 < K) {
            if (A_SCALE) load16s(A, aoff + k0 + 64, asc, a0r, a1r);
            else         load16<A_BF>(A, aoff + k0 + 64, a0r, a1r);
            load16<W_BF>(W, woff + k0 + 64, w0r, w1r);
        }
        #pragma unroll
        for (int kk = 0; kk < 64; kk += 32) {
            short8 a0 = *(const short8*)&As[(mh + l16) * 72 + kk + quad * 8];
            short8 a1 = *(const short8*)&As[(mh + 16 + l16) * 72 + kk + quad * 8];
            short8 b0 = *(const short8*)&Ws[(nh + l16) * 72 + kk + quad * 8];
            short8 b1 = *(const short8*)&Ws[(nh + 16 + l16) * 72 + kk + quad * 8];
            acc00 = __builtin_amdgcn_mfma_f32_16x16x32_bf16(a0, b0, acc00, 0, 0, 0);
            acc01 = __builtin_amdgcn_mfma_f32_16x16x32_bf16(a0, b1, acc01, 0, 0, 0);
            acc10 = __builtin_amdgcn_mfma_f32_16x16x32_bf16(a1, b0, acc10, 0, 0, 0);
            acc11 = __builtin_amdgcn_mfma_f32_16x16x32_bf16(a1, b1, acc11, 0, 0, 0);
        }
        __syncthreads();
    }

    const int col0 = bn + nh + l16;
    const int col1 = col0 + 16;
    float bias0 = bias ? bias[col0] : 0.f;
    float bias1 = bias ? bias[col1] : 0.f;

    f32x4 accs[2][2] = {{acc00, acc01}, {acc10, acc11}};
    #pragma unroll
    for (int mt = 0; mt < 2; ++mt) {
        #pragma unroll
        for (int r = 0; r < 4; ++r) {
            int row = bm + mh + mt * 16 + quad * 4 + r;
            size_t rowoff = (size_t)row * ldc;
            float v0 = accs[mt][0][r] + bias0;
            float v1 = accs[mt][1][r] + bias1;
            if (EPI == 1) { v0 = __expf(2.f * v0); v1 = __expf(2.f * v1); }
            if (EPI == 3) { v0 += partial[rowoff + col0]; v1 += partial[rowoff + col1]; }
            if (EPI == 2) {
                ushort_t* C = (ushort_t*)Cv;
                C[rowoff + col0] = f2bf(v0);
                C[rowoff + col1] = f2bf(v1);
            } else {
                float* C = (float*)Cv;
                C[rowoff + col0] = v0;
                C[rowoff + col1] = v1;
            }
        }
    }
}

// ---------------------------------------------------------------------------
// K1: fused front (640 GEMM blocks)
// [0,64)    Ew = exp(2*(inp@Wq^T + bq))
// [64,320)  Eu = exp(2*(ctx@Wc^T))
// [320,576) GT[b][n,s] = sum_d WL[n,d]*ctx[b][s,d]  (bf16)
// [576,640) Y0 = inp@WR^T + bout
// ---------------------------------------------------------------------------
__global__ __launch_bounds__(256) void fused_front(
    const float* __restrict__ inp, const float* __restrict__ ctx,
    const float* __restrict__ Wq, const float* __restrict__ bq,
    const float* __restrict__ Wc, const float* __restrict__ Wout,
    const float* __restrict__ bout,
    float* __restrict__ Ew, float* __restrict__ Eu, float* __restrict__ Y0,
    ushort_t* __restrict__ GT)
{
    __shared__ ushort_t As[64 * 72];
    __shared__ ushort_t Ws[64 * 72];
    const int bid = blockIdx.x;

    if (bid < 64) {
        gemm_body<false, false, 1>(As, Ws, inp, Wq, bq, nullptr, Ew,
                                   512, 512, 512, 512, (bid & 7) * 64, (bid >> 3) * 64);
    } else if (bid < 320) {
        int i = bid - 64;
        gemm_body<false, false, 1>(As, Ws, ctx, Wc, nullptr, nullptr, Eu,
                                   512, 512, 512, 512, (i & 31) * 64, (i >> 5) * 64);
    } else if (bid < 576) {
        int i = bid - 320;
        int b = i >> 6, j = i & 63;
        gemm_body<false, false, 2>(As, Ws, Wout, ctx + (size_t)b * 262144, nullptr,
                                   nullptr, GT + (size_t)b * 262144,
                                   512, 1024, 512, 512, (j & 7) * 64, (j >> 3) * 64);
    } else {
        int i = bid - 576;
        gemm_body<false, false, 0>(As, Ws, inp, Wout + 512, bout, nullptr, Y0,
                                   512, 512, 1024, 512, (i & 7) * 64, (i >> 3) * 64);
    }
}

// ---------------------------------------------------------------------------
// K2: E[b,t,s] = exp(V - 2*sum_d v[d]/(1 + Ew[b,t,d]*Eu[b,s,d])),  V = sum v[d]
// (R7 structure verbatim: k across lanes, paired rcp, shuffle reduce tail.)
// Grid (64, 8, 4) = 2048 blocks = 8 blocks/CU. Tail applies __expf before the
// store: |S| <= sum|v| ~ 18 so no max-subtraction needed for fp32 exp.
// ---------------------------------------------------------------------------
__global__ __launch_bounds__(256) void align_kernel(
    const float* __restrict__ Ew, const float* __restrict__ Eu,
    const float* __restrict__ v, float* __restrict__ out)
{
    const int lane = threadIdx.x & 63, wave = threadIdx.x >> 6;
    const int b = blockIdx.z;
    const int t0 = blockIdx.y * 16 + wave * 4;
    const int s0 = blockIdx.x * 8;

    const float* wp = Ew + (((size_t)(b * 128 + t0)) << 9);
    const float* up = Eu + (((size_t)(b * 512 + s0)) << 9);

    float acc[4][8];
    #pragma unroll
    for (int i = 0; i < 4; ++i)
        #pragma unroll
        for (int j = 0; j < 8; ++j) acc[i][j] = 0.f;
    float vsum = 0.f;

    for (int k0 = 0; k0 < 512; k0 += 128) {
        float va = v[k0 + lane];
        float vb = v[k0 + 64 + lane];
        vsum += va + vb;
        float wa[4], wb[4];
        #pragma unroll
        for (int i = 0; i < 4; ++i) {
            wa[i] = wp[i * 512 + k0 + lane];
            wb[i] = wp[i * 512 + k0 + 64 + lane];
        }
        #pragma unroll
        for (int j = 0; j < 8; ++j) {
            const float* u = up + ((size_t)j << 9) + k0 + lane;
            float ua = u[0];
            float ub = u[64];
            #pragma unroll
            for (int i = 0; i < 4; ++i) {
                float A = fmaf(wa[i], ua, 1.f);     // 1 + Ew_a*Eu_a  (>= 1)
                float B = fmaf(wb[i], ub, 1.f);     // 1 + Ew_b*Eu_b  (>= 1)
                float num = fmaf(va, B, vb * A);    // v_a*B + v_b*A
                float r = __builtin_amdgcn_rcpf(A * B);  // den safe in fp32
                acc[i][j] = fmaf(num, r, acc[i][j]);
            }
        }
    }

    float V = vsum;
    #pragma unroll
    for (int off = 32; off; off >>= 1) V += __shfl_xor(V, off, 64);

    float r0 = 0.f, r1 = 0.f, r2 = 0.f, r3 = 0.f;
    #pragma unroll
    for (int j = 0; j < 8; ++j) {
        float a0 = acc[0][j], a1 = acc[1][j], a2 = acc[2][j], a3 = acc[3][j];
        #pragma unroll
        for (int off = 32; off; off >>= 1) {
            a0 += __shfl_xor(a0, off, 64);
            a1 += __shfl_xor(a1, off, 64);
            a2 += __shfl_xor(a2, off, 64);
            a3 += __shfl_xor(a3, off, 64);
        }
        if (lane == j) {
            r0 = fmaf(-2.f, a0, V);
            r1 = fmaf(-2.f, a1, V);
            r2 = fmaf(-2.f, a2, V);
            r3 = fmaf(-2.f, a3, V);
        }
    }
    if (lane < 8) {
        size_t o = (((size_t)(b * 128 + t0)) << 9) + s0 + lane;
        out[o]        = __expf(r0);
        out[o + 512]  = __expf(r1);
        out[o + 1024] = __expf(r2);
        out[o + 1536] = __expf(r3);
    }
}

// ---------------------------------------------------------------------------
// K3: attn = (E * rinv)_bf16 @ GT^T + Y0. Per-batch M=128, N=512, K=512.
// Grid (2,8,4). Block-local prepass: rowsum of E over 64 rows -> rinv[] in
// LDS (16 rows/wave, 8 elems/lane, shuffle-reduce; no atomics).
// Blocks with y==0 also write alignv = E * rinv (fp32).
// ---------------------------------------------------------------------------
__global__ __launch_bounds__(256) void gemm_att_sm(
    const float* __restrict__ E, const ushort_t* __restrict__ GT,
    const float* __restrict__ Y0, float* __restrict__ attn,
    float* __restrict__ alignv)
{
    __shared__ ushort_t As[64 * 72];
    __shared__ ushort_t Ws[64 * 72];
    __shared__ float rinv[64];
    const int b = blockIdx.z;
    const int bm = blockIdx.x * 64;
    const int tid = threadIdx.x;
    const int wv = tid >> 6, ln = tid & 63;

    const float* Eb = E + (((size_t)(b * 128 + bm)) << 9);

    // prepass: rinv[r] = 1 / sum_s E[bm+r][s], 16 rows per wave
    #pragma unroll 4
    for (int r0 = 0; r0 < 16; ++r0) {
        const int row = wv * 16 + r0;
        const float* er = Eb + ((size_t)row << 9);
        float s = 0.f;
        #pragma unroll
        for (int i = 0; i < 8; ++i) s += er[ln + 64 * i];
        #pragma unroll
        for (int off = 32; off; off >>= 1) s += __shfl_xor(s, off, 64);
        if (ln == 0) rinv[row] = 1.0f / s;
    }
    __syncthreads();

    gemm_body<false, true, 3, true>(As, Ws,
                                    Eb, GT + (size_t)b * 262144,
                                    nullptr, Y0 + (size_t)b * 65536 + (size_t)bm * 512,
                                    attn + (size_t)b * 65536 + (size_t)bm * 512,
                                    512, 512, 512, 512, 0, blockIdx.y * 64, rinv);

    if (blockIdx.y == 0) {
        float* av = alignv + (size_t)b * 65536 + (size_t)bm * 512;
        for (int i = tid; i < 8192; i += 256) {          // 64 rows * 128 float4
            int r = i >> 7, c4 = i & 127;
            float4 e = ((const float4*)(Eb + ((size_t)r << 9)))[c4];
            float s = rinv[r];
            e.x *= s; e.y *= s; e.z *= s; e.w *= s;
            ((float4*)(av + ((size_t)r << 9)))[c4] = e;
        }
    }
}

// ---------------------------------------------------------------------------
extern "C" void kernel_launch(void* const* d_in, const int* in_sizes, int n_in,
                              void* d_out, int out_size, void* d_ws, size_t ws_size,
                              hipStream_t stream)
{
    const float* inp  = (const float*)d_in[0];   // (4,128,512)
    const float* ctx  = (const float*)d_in[1];   // (4,512,512)
    const float* Wq   = (const float*)d_in[2];   // (512,512)
    const float* bq   = (const float*)d_in[3];   // (512)
    const float* Wc   = (const float*)d_in[4];   // (512,512)
    const float* v    = (const float*)d_in[5];   // (512)
    const float* Wout = (const float*)d_in[6];   // (512,1024)
    const float* bout = (const float*)d_in[7];   // (512)

    float* out    = (float*)d_out;
    float* attn   = out;              // 262144 floats
    float* alignv = out + 262144;     // 262144 floats

    float* ws = (float*)d_ws;
    float* Ew   = ws;                          // 262144 f
    float* Eu   = ws + 262144;                 // 1048576 f
    float* Y0   = ws + 1310720;                // 262144 f
    float* E    = ws + 1572864;                // 262144 f (exp of raw scores)
    ushort_t* GT = (ushort_t*)(ws + 1835008);  // 1048576 u16 (= 524288 f)

    fused_front<<<dim3(640), 256, 0, stream>>>(inp, ctx, Wq, bq, Wc, Wout, bout,
                                               Ew, Eu, Y0, GT);
    align_kernel<<<dim3(64, 8, 4), 256, 0, stream>>>(Ew, Eu, v, E);
    gemm_att_sm<<<dim3(2, 8, 4), 256, 0, stream>>>(E, GT, Y0, attn, alignv);
}

// Round 5
// 116.622 us; speedup vs baseline: 1.1664x; 1.1664x over previous
//
#include <hip/hip_runtime.h>
#include <hip/hip_bf16.h>
#include <math.h>

// B=4, T=128, S=512, D=512. Outputs: attn_h (4,128,512) then align (4,128,512), fp32.
// 5-kernel pipeline (R10 = R7 + K0 bf16 pre-convert, all-bf16 K1 staging):
//   K0 cvt_bf16 (1152): inp/ctx/Wq/Wc/Wout -> bf16 once (removes per-tile
//      fp32->bf16 cvt VALU + halves staging bytes in K1; m80: staging is the
//      VALU bottleneck of this GEMM shape).
//   K1 fused_front (640): Ew=exp(2(inp@Wq^T+bq)), Eu=exp(2 ctx@Wc^T),
//      GT[b]=(WL@ctx_b^T) bf16, Y0=inp@WR^T+bout   (all operands bf16)
//   K2 align (2048): Sraw[b,t,s] = V - 2*sum_d v[d]/(1+Ew*Eu)  (== sum v*tanh)
//      paired rcp (1 rcp / 2 d-elems), k across lanes  [R7 verbatim]
//   K3 softmax (512): alignv (fp32, d_out) + P_bf (bf16, ws)   [R7 verbatim]
//   K4 gemm_att (64): attn = P_bf @ GT^T + Y0 (MFMA, K=512)    [R7 verbatim]

typedef __attribute__((ext_vector_type(8))) short short8;
typedef __attribute__((ext_vector_type(4))) float f32x4;
typedef unsigned short ushort_t;

static __device__ __forceinline__ unsigned short f2bf(float x) {
    union { __hip_bfloat16 h; unsigned short u; } c;
    c.h = __float2bfloat16(x);
    return c.u;
}
static __device__ __forceinline__ int bf2x(float lo, float hi) {
    return (int)(((unsigned)f2bf(hi) << 16) | (unsigned)f2bf(lo));
}

template<bool BF>
static __device__ __forceinline__ void load16(const void* base, size_t elemoff,
                                              int4& r0, int4& r1) {
    if (BF) {
        const int4* p = (const int4*)((const ushort_t*)base + elemoff);
        r0 = p[0]; r1 = p[1];
    } else {
        const float4* p = (const float4*)((const float*)base + elemoff);
        float4 a = p[0], b = p[1], c = p[2], d = p[3];
        r0.x = bf2x(a.x, a.y); r0.y = bf2x(a.z, a.w);
        r0.z = bf2x(b.x, b.y); r0.w = bf2x(b.z, b.w);
        r1.x = bf2x(c.x, c.y); r1.y = bf2x(c.z, c.w);
        r1.z = bf2x(d.x, d.y); r1.w = bf2x(d.z, d.w);
    }
}

// ---------------------------------------------------------------------------
// MFMA NT GEMM tile: C[m,n] = sum_k A[m,k]*W[n,k] (+bias). 64x64 tile, BK=64,
// 256 thr = 4 waves (2x2 of 32x32), 2x2 MFMA 16x16x32 per 32-K step.
// LDS rows padded to 72 bf16 (<=2-way bank aliasing on b128 = free).
// EPI: 0 fp32+bias; 1 fp32 exp(2*(x+bias)); 2 bf16; 3 fp32 + partial[].
// ---------------------------------------------------------------------------
template<bool A_BF, bool W_BF, int EPI>
static __device__ __forceinline__ void gemm_body(
    ushort_t* As, ushort_t* Ws,
    const void* A, const void* W, const float* bias, const float* partial,
    void* Cv, int K, int lda, int ldw, int ldc, int bm, int bn)
{
    const int tid = threadIdx.x;
    const int wave = tid >> 6, lane = tid & 63;
    const int mh = (wave & 1) * 32, nh = (wave >> 1) * 32;
    const int quad = lane >> 4, l16 = lane & 15;
    const int srow = tid >> 2, schunk = tid & 3;

    const size_t aoff = (size_t)(bm + srow) * lda + schunk * 16;
    const size_t woff = (size_t)(bn + srow) * ldw + schunk * 16;
    int4* AsW = (int4*)&As[srow * 72 + schunk * 16];
    int4* WsW = (int4*)&Ws[srow * 72 + schunk * 16];

    f32x4 acc00 = {0.f, 0.f, 0.f, 0.f}, acc01 = acc00, acc10 = acc00, acc11 = acc00;

    int4 a0r, a1r, w0r, w1r;
    load16<A_BF>(A, aoff, a0r, a1r);
    load16<W_BF>(W, woff, w0r, w1r);

    for (int k0 = 0; k0 < K; k0 += 64) {
        AsW[0] = a0r; AsW[1] = a1r;
        WsW[0] = w0r; WsW[1] = w1r;
        __syncthreads();
        if (k0 + 64 < K) {
            load16<A_BF>(A, aoff + k0 + 64, a0r, a1r);
            load16<W_BF>(W, woff + k0 + 64, w0r, w1r);
        }
        #pragma unroll
        for (int kk = 0; kk < 64; kk += 32) {
            short8 a0 = *(const short8*)&As[(mh + l16) * 72 + kk + quad * 8];
            short8 a1 = *(const short8*)&As[(mh + 16 + l16) * 72 + kk + quad * 8];
            short8 b0 = *(const short8*)&Ws[(nh + l16) * 72 + kk + quad * 8];
            short8 b1 = *(const short8*)&Ws[(nh + 16 + l16) * 72 + kk + quad * 8];
            acc00 = __builtin_amdgcn_mfma_f32_16x16x32_bf16(a0, b0, acc00, 0, 0, 0);
            acc01 = __builtin_amdgcn_mfma_f32_16x16x32_bf16(a0, b1, acc01, 0, 0, 0);
            acc10 = __builtin_amdgcn_mfma_f32_16x16x32_bf16(a1, b0, acc10, 0, 0, 0);
            acc11 = __builtin_amdgcn_mfma_f32_16x16x32_bf16(a1, b1, acc11, 0, 0, 0);
        }
        __syncthreads();
    }

    const int col0 = bn + nh + l16;
    const int col1 = col0 + 16;
    float bias0 = bias ? bias[col0] : 0.f;
    float bias1 = bias ? bias[col1] : 0.f;

    f32x4 accs[2][2] = {{acc00, acc01}, {acc10, acc11}};
    #pragma unroll
    for (int mt = 0; mt < 2; ++mt) {
        #pragma unroll
        for (int r = 0; r < 4; ++r) {
            int row = bm + mh + mt * 16 + quad * 4 + r;
            size_t rowoff = (size_t)row * ldc;
            float v0 = accs[mt][0][r] + bias0;
            float v1 = accs[mt][1][r] + bias1;
            if (EPI == 1) { v0 = __expf(2.f * v0); v1 = __expf(2.f * v1); }
            if (EPI == 3) { v0 += partial[rowoff + col0]; v1 += partial[rowoff + col1]; }
            if (EPI == 2) {
                ushort_t* C = (ushort_t*)Cv;
                C[rowoff + col0] = f2bf(v0);
                C[rowoff + col1] = f2bf(v1);
            } else {
                float* C = (float*)Cv;
                C[rowoff + col0] = v0;
                C[rowoff + col1] = v1;
            }
        }
    }
}

// ---------------------------------------------------------------------------
// K0: fp32 -> bf16 pre-convert. 2048 elems/block (256 thr x 8).
// [0,128) inp | [128,640) ctx | [640,768) Wq | [768,896) Wc | [896,1152) Wout
// ---------------------------------------------------------------------------
__global__ __launch_bounds__(256) void cvt_bf16(
    const float* __restrict__ inp, const float* __restrict__ ctx,
    const float* __restrict__ Wq, const float* __restrict__ Wc,
    const float* __restrict__ Wout,
    ushort_t* __restrict__ inpb, ushort_t* __restrict__ ctxb,
    ushort_t* __restrict__ Wqb, ushort_t* __restrict__ Wcb,
    ushort_t* __restrict__ Woutb)
{
    const int bid = blockIdx.x;
    const float* src; ushort_t* dst; int base;
    if (bid < 128)      { src = inp;  dst = inpb;  base = bid; }
    else if (bid < 640) { src = ctx;  dst = ctxb;  base = bid - 128; }
    else if (bid < 768) { src = Wq;   dst = Wqb;   base = bid - 640; }
    else if (bid < 896) { src = Wc;   dst = Wcb;   base = bid - 768; }
    else                { src = Wout; dst = Woutb; base = bid - 896; }
    const size_t off = (size_t)base * 2048 + (size_t)threadIdx.x * 8;
    const float4* s = (const float4*)(src + off);
    float4 a = s[0], b = s[1];
    int4 r;
    r.x = bf2x(a.x, a.y); r.y = bf2x(a.z, a.w);
    r.z = bf2x(b.x, b.y); r.w = bf2x(b.z, b.w);
    *(int4*)(dst + off) = r;
}

// ---------------------------------------------------------------------------
// K1: fused front (640 GEMM blocks), all operands bf16
// [0,64)    Ew = exp(2*(inp@Wq^T + bq))
// [64,320)  Eu = exp(2*(ctx@Wc^T))
// [320,576) GT[b][n,s] = sum_d WL[n,d]*ctx[b][s,d]  (bf16)
// [576,640) Y0 = inp@WR^T + bout
// ---------------------------------------------------------------------------
__global__ __launch_bounds__(256) void fused_front(
    const ushort_t* __restrict__ inpb, const ushort_t* __restrict__ ctxb,
    const ushort_t* __restrict__ Wqb, const float* __restrict__ bq,
    const ushort_t* __restrict__ Wcb, const ushort_t* __restrict__ Woutb,
    const float* __restrict__ bout,
    float* __restrict__ Ew, float* __restrict__ Eu, float* __restrict__ Y0,
    ushort_t* __restrict__ GT)
{
    __shared__ ushort_t As[64 * 72];
    __shared__ ushort_t Ws[64 * 72];
    const int bid = blockIdx.x;

    if (bid < 64) {
        gemm_body<true, true, 1>(As, Ws, inpb, Wqb, bq, nullptr, Ew,
                                 512, 512, 512, 512, (bid & 7) * 64, (bid >> 3) * 64);
    } else if (bid < 320) {
        int i = bid - 64;
        gemm_body<true, true, 1>(As, Ws, ctxb, Wcb, nullptr, nullptr, Eu,
                                 512, 512, 512, 512, (i & 31) * 64, (i >> 5) * 64);
    } else if (bid < 576) {
        int i = bid - 320;
        int b = i >> 6, j = i & 63;
        gemm_body<true, true, 2>(As, Ws, Woutb, ctxb + (size_t)b * 262144, nullptr,
                                 nullptr, GT + (size_t)b * 262144,
                                 512, 1024, 512, 512, (j & 7) * 64, (j >> 3) * 64);
    } else {
        int i = bid - 576;
        gemm_body<true, true, 0>(As, Ws, inpb, Woutb + 512, bout, nullptr, Y0,
                                 512, 512, 1024, 512, (i & 7) * 64, (i >> 3) * 64);
    }
}

// ---------------------------------------------------------------------------
// K2: Sraw[b,t,s] = V - 2*sum_d v[d]/(1 + Ew[b,t,d]*Eu[b,s,d]),  V = sum v[d]
// Wave w: 4 t's (t0 = by*16 + w*4), 8 s's. Grid (64, 8, 4) = 2048 blocks
// (exactly fills the GPU: 8 blocks/CU, 2048 thr/CU). [R7 verbatim]
// ---------------------------------------------------------------------------
__global__ __launch_bounds__(256) void align_kernel(
    const float* __restrict__ Ew, const float* __restrict__ Eu,
    const float* __restrict__ v, float* __restrict__ out)
{
    const int lane = threadIdx.x & 63, wave = threadIdx.x >> 6;
    const int b = blockIdx.z;
    const int t0 = blockIdx.y * 16 + wave * 4;
    const int s0 = blockIdx.x * 8;

    const float* wp = Ew + (((size_t)(b * 128 + t0)) << 9);
    const float* up = Eu + (((size_t)(b * 512 + s0)) << 9);

    float acc[4][8];
    #pragma unroll
    for (int i = 0; i < 4; ++i)
        #pragma unroll
        for (int j = 0; j < 8; ++j) acc[i][j] = 0.f;
    float vsum = 0.f;

    for (int k0 = 0; k0 < 512; k0 += 128) {
        float va = v[k0 + lane];
        float vb = v[k0 + 64 + lane];
        vsum += va + vb;
        float wa[4], wb[4];
        #pragma unroll
        for (int i = 0; i < 4; ++i) {
            wa[i] = wp[i * 512 + k0 + lane];
            wb[i] = wp[i * 512 + k0 + 64 + lane];
        }
        #pragma unroll
        for (int j = 0; j < 8; ++j) {
            const float* u = up + ((size_t)j << 9) + k0 + lane;
            float ua = u[0];
            float ub = u[64];
            #pragma unroll
            for (int i = 0; i < 4; ++i) {
                float A = fmaf(wa[i], ua, 1.f);     // 1 + Ew_a*Eu_a  (>= 1)
                float B = fmaf(wb[i], ub, 1.f);     // 1 + Ew_b*Eu_b  (>= 1)
                float num = fmaf(va, B, vb * A);    // v_a*B + v_b*A
                float r = __builtin_amdgcn_rcpf(A * B);  // den safe in fp32
                acc[i][j] = fmaf(num, r, acc[i][j]);
            }
        }
    }

    float V = vsum;
    #pragma unroll
    for (int off = 32; off; off >>= 1) V += __shfl_xor(V, off, 64);

    float r0 = 0.f, r1 = 0.f, r2 = 0.f, r3 = 0.f;
    #pragma unroll
    for (int j = 0; j < 8; ++j) {
        float a0 = acc[0][j], a1 = acc[1][j], a2 = acc[2][j], a3 = acc[3][j];
        #pragma unroll
        for (int off = 32; off; off >>= 1) {
            a0 += __shfl_xor(a0, off, 64);
            a1 += __shfl_xor(a1, off, 64);
            a2 += __shfl_xor(a2, off, 64);
            a3 += __shfl_xor(a3, off, 64);
        }
        if (lane == j) {
            r0 = fmaf(-2.f, a0, V);
            r1 = fmaf(-2.f, a1, V);
            r2 = fmaf(-2.f, a2, V);
            r3 = fmaf(-2.f, a3, V);
        }
    }
    if (lane < 8) {
        size_t o = (((size_t)(b * 128 + t0)) << 9) + s0 + lane;
        out[o] = r0;
        out[o + 512] = r1;
        out[o + 1024] = r2;
        out[o + 1536] = r3;
    }
}

// ---------------------------------------------------------------------------
// K3: softmax over rows of 512. Reads Sraw, writes fp32 alignv + bf16 P.
// [R7 verbatim]
// ---------------------------------------------------------------------------
__global__ __launch_bounds__(256) void softmax_512(
    const float* __restrict__ Sraw, float* __restrict__ alignv,
    ushort_t* __restrict__ pbf)
{
    const int row = blockIdx.x;
    const float* p = Sraw + ((size_t)row << 9);
    float* a = alignv + ((size_t)row << 9);
    ushort_t* q = pbf + ((size_t)row << 9);
    const int tid = threadIdx.x;
    float x0 = p[tid];
    float x1 = p[tid + 256];

    float m = fmaxf(x0, x1);
    #pragma unroll
    for (int off = 32; off > 0; off >>= 1)
        m = fmaxf(m, __shfl_xor(m, off, 64));
    __shared__ float redm[4];
    __shared__ float reds[4];
    const int wave = tid >> 6;
    if ((tid & 63) == 0) redm[wave] = m;
    __syncthreads();
    m = fmaxf(fmaxf(redm[0], redm[1]), fmaxf(redm[2], redm[3]));

    float e0 = __expf(x0 - m);
    float e1 = __expf(x1 - m);
    float s = e0 + e1;
    #pragma unroll
    for (int off = 32; off > 0; off >>= 1)
        s += __shfl_xor(s, off, 64);
    if ((tid & 63) == 0) reds[wave] = s;
    __syncthreads();
    s = reds[0] + reds[1] + reds[2] + reds[3];
    float r = 1.0f / s;
    float p0 = e0 * r, p1 = e1 * r;
    a[tid] = p0;
    a[tid + 256] = p1;
    q[tid] = f2bf(p0);
    q[tid + 256] = f2bf(p1);
}

// ---------------------------------------------------------------------------
// K4: attn = P_bf @ GT^T + Y0. Per-batch M=128, N=512, K=512. Grid (2,8,4).
// [R7 verbatim]
// ---------------------------------------------------------------------------
__global__ __launch_bounds__(256) void gemm_att(
    const ushort_t* __restrict__ P, const ushort_t* __restrict__ GT,
    const float* __restrict__ Y0, float* __restrict__ attn)
{
    __shared__ ushort_t As[64 * 72];
    __shared__ ushort_t Ws[64 * 72];
    const int b = blockIdx.z;
    gemm_body<true, true, 3>(As, Ws,
                             P + (size_t)b * 65536, GT + (size_t)b * 262144,
                             nullptr, Y0 + (size_t)b * 65536,
                             attn + (size_t)b * 65536,
                             512, 512, 512, 512, blockIdx.x * 64, blockIdx.y * 64);
}

// ---------------------------------------------------------------------------
extern "C" void kernel_launch(void* const* d_in, const int* in_sizes, int n_in,
                              void* d_out, int out_size, void* d_ws, size_t ws_size,
                              hipStream_t stream)
{
    const float* inp  = (const float*)d_in[0];   // (4,128,512)
    const float* ctx  = (const float*)d_in[1];   // (4,512,512)
    const float* Wq   = (const float*)d_in[2];   // (512,512)
    const float* bq   = (const float*)d_in[3];   // (512)
    const float* Wc   = (const float*)d_in[4];   // (512,512)
    const float* v    = (const float*)d_in[5];   // (512)
    const float* Wout = (const float*)d_in[6];   // (512,1024)
    const float* bout = (const float*)d_in[7];   // (512)

    float* out    = (float*)d_out;
    float* attn   = out;              // 262144 floats
    float* alignv = out + 262144;     // 262144 floats

    float* ws = (float*)d_ws;
    float* Ew   = ws;                             // 262144 f
    float* Eu   = ws + 262144;                    // 1048576 f
    float* Y0   = ws + 1310720;                   // 262144 f
    float* Sraw = ws + 1572864;                   // 262144 f
    ushort_t* GT   = (ushort_t*)(ws + 1835008);   // 1048576 u16 (= 524288 f)
    ushort_t* P_bf = (ushort_t*)(ws + 2359296);   // 262144 u16 (= 131072 f)
    ushort_t* inpb  = (ushort_t*)(ws + 2490368);  // 262144 u16
    ushort_t* ctxb  = (ushort_t*)(ws + 2621440);  // 1048576 u16
    ushort_t* Wqb   = (ushort_t*)(ws + 3145728);  // 262144 u16
    ushort_t* Wcb   = (ushort_t*)(ws + 3276800);  // 262144 u16
    ushort_t* Woutb = (ushort_t*)(ws + 3407872);  // 524288 u16

    cvt_bf16<<<dim3(1152), 256, 0, stream>>>(inp, ctx, Wq, Wc, Wout,
                                             inpb, ctxb, Wqb, Wcb, Woutb);
    fused_front<<<dim3(640), 256, 0, stream>>>(inpb, ctxb, Wqb, bq, Wcb, Woutb,
                                               bout, Ew, Eu, Y0, GT);
    align_kernel<<<dim3(64, 8, 4), 256, 0, stream>>>(Ew, Eu, v, Sraw);
    softmax_512<<<dim3(512), 256, 0, stream>>>(Sraw, alignv, P_bf);
    gemm_att<<<dim3(2, 8, 4), 256, 0, stream>>>(P_bf, GT, Y0, attn);
}

// Round 6
// 110.277 us; speedup vs baseline: 1.2335x; 1.0575x over previous
//
#include <hip/hip_runtime.h>
#include <hip/hip_bf16.h>
#include <math.h>

// B=4, T=128, S=512, D=512. Outputs: attn_h (4,128,512) then align (4,128,512), fp32.
// 5-kernel pipeline (R11 = R10 + halving-butterfly K2 tail + maxless K3):
//   K0 cvt_bf16 (1152): inp/ctx/Wq/Wc/Wout -> bf16 once
//   K1 fused_front (640): Ew=exp(2(inp@Wq^T+bq)), Eu=exp(2 ctx@Wc^T),
//      GT[b]=(WL@ctx_b^T) bf16, Y0=inp@WR^T+bout   (all operands bf16)
//   K2 align (2048): E[b,t,s] = exp(V - 2*sum_d v[d]/(1+Ew*Eu)) (= exp(sum v*tanh))
//      paired rcp; tail = multi-value halving butterfly (32 shuffles vs 192);
//      exp applied in tail (|S|<=sum|v|~18, fp32-safe without max-subtract, R9-proven).
//   K3 normalize (512): rowsum + alignv=E/s (fp32) + P_bf=bf16(E/s)  (no max pass)
//   K4 gemm_att (64): attn = P_bf @ GT^T + Y0 (MFMA, K=512)

typedef __attribute__((ext_vector_type(8))) short short8;
typedef __attribute__((ext_vector_type(4))) float f32x4;
typedef unsigned short ushort_t;

static __device__ __forceinline__ unsigned short f2bf(float x) {
    union { __hip_bfloat16 h; unsigned short u; } c;
    c.h = __float2bfloat16(x);
    return c.u;
}
static __device__ __forceinline__ int bf2x(float lo, float hi) {
    return (int)(((unsigned)f2bf(hi) << 16) | (unsigned)f2bf(lo));
}

template<bool BF>
static __device__ __forceinline__ void load16(const void* base, size_t elemoff,
                                              int4& r0, int4& r1) {
    if (BF) {
        const int4* p = (const int4*)((const ushort_t*)base + elemoff);
        r0 = p[0]; r1 = p[1];
    } else {
        const float4* p = (const float4*)((const float*)base + elemoff);
        float4 a = p[0], b = p[1], c = p[2], d = p[3];
        r0.x = bf2x(a.x, a.y); r0.y = bf2x(a.z, a.w);
        r0.z = bf2x(b.x, b.y); r0.w = bf2x(b.z, b.w);
        r1.x = bf2x(c.x, c.y); r1.y = bf2x(c.z, c.w);
        r1.z = bf2x(d.x, d.y); r1.w = bf2x(d.z, d.w);
    }
}

// ---------------------------------------------------------------------------
// MFMA NT GEMM tile: C[m,n] = sum_k A[m,k]*W[n,k] (+bias). 64x64 tile, BK=64,
// 256 thr = 4 waves (2x2 of 32x32), 2x2 MFMA 16x16x32 per 32-K step.
// LDS rows padded to 72 bf16 (<=2-way bank aliasing on b128 = free).
// EPI: 0 fp32+bias; 1 fp32 exp(2*(x+bias)); 2 bf16; 3 fp32 + partial[].
// ---------------------------------------------------------------------------
template<bool A_BF, bool W_BF, int EPI>
static __device__ __forceinline__ void gemm_body(
    ushort_t* As, ushort_t* Ws,
    const void* A, const void* W, const float* bias, const float* partial,
    void* Cv, int K, int lda, int ldw, int ldc, int bm, int bn)
{
    const int tid = threadIdx.x;
    const int wave = tid >> 6, lane = tid & 63;
    const int mh = (wave & 1) * 32, nh = (wave >> 1) * 32;
    const int quad = lane >> 4, l16 = lane & 15;
    const int srow = tid >> 2, schunk = tid & 3;

    const size_t aoff = (size_t)(bm + srow) * lda + schunk * 16;
    const size_t woff = (size_t)(bn + srow) * ldw + schunk * 16;
    int4* AsW = (int4*)&As[srow * 72 + schunk * 16];
    int4* WsW = (int4*)&Ws[srow * 72 + schunk * 16];

    f32x4 acc00 = {0.f, 0.f, 0.f, 0.f}, acc01 = acc00, acc10 = acc00, acc11 = acc00;

    int4 a0r, a1r, w0r, w1r;
    load16<A_BF>(A, aoff, a0r, a1r);
    load16<W_BF>(W, woff, w0r, w1r);

    for (int k0 = 0; k0 < K; k0 += 64) {
        AsW[0] = a0r; AsW[1] = a1r;
        WsW[0] = w0r; WsW[1] = w1r;
        __syncthreads();
        if (k0 + 64 < K) {
            load16<A_BF>(A, aoff + k0 + 64, a0r, a1r);
            load16<W_BF>(W, woff + k0 + 64, w0r, w1r);
        }
        #pragma unroll
        for (int kk = 0; kk < 64; kk += 32) {
            short8 a0 = *(const short8*)&As[(mh + l16) * 72 + kk + quad * 8];
            short8 a1 = *(const short8*)&As[(mh + 16 + l16) * 72 + kk + quad * 8];
            short8 b0 = *(const short8*)&Ws[(nh + l16) * 72 + kk + quad * 8];
            short8 b1 = *(const short8*)&Ws[(nh + 16 + l16) * 72 + kk + quad * 8];
            acc00 = __builtin_amdgcn_mfma_f32_16x16x32_bf16(a0, b0, acc00, 0, 0, 0);
            acc01 = __builtin_amdgcn_mfma_f32_16x16x32_bf16(a0, b1, acc01, 0, 0, 0);
            acc10 = __builtin_amdgcn_mfma_f32_16x16x32_bf16(a1, b0, acc10, 0, 0, 0);
            acc11 = __builtin_amdgcn_mfma_f32_16x16x32_bf16(a1, b1, acc11, 0, 0, 0);
        }
        __syncthreads();
    }

    const int col0 = bn + nh + l16;
    const int col1 = col0 + 16;
    float bias0 = bias ? bias[col0] : 0.f;
    float bias1 = bias ? bias[col1] : 0.f;

    f32x4 accs[2][2] = {{acc00, acc01}, {acc10, acc11}};
    #pragma unroll
    for (int mt = 0; mt < 2; ++mt) {
        #pragma unroll
        for (int r = 0; r < 4; ++r) {
            int row = bm + mh + mt * 16 + quad * 4 + r;
            size_t rowoff = (size_t)row * ldc;
            float v0 = accs[mt][0][r] + bias0;
            float v1 = accs[mt][1][r] + bias1;
            if (EPI == 1) { v0 = __expf(2.f * v0); v1 = __expf(2.f * v1); }
            if (EPI == 3) { v0 += partial[rowoff + col0]; v1 += partial[rowoff + col1]; }
            if (EPI == 2) {
                ushort_t* C = (ushort_t*)Cv;
                C[rowoff + col0] = f2bf(v0);
                C[rowoff + col1] = f2bf(v1);
            } else {
                float* C = (float*)Cv;
                C[rowoff + col0] = v0;
                C[rowoff + col1] = v1;
            }
        }
    }
}

// ---------------------------------------------------------------------------
// K0: fp32 -> bf16 pre-convert. 2048 elems/block (256 thr x 8).
// [0,128) inp | [128,640) ctx | [640,768) Wq | [768,896) Wc | [896,1152) Wout
// ---------------------------------------------------------------------------
__global__ __launch_bounds__(256) void cvt_bf16(
    const float* __restrict__ inp, const float* __restrict__ ctx,
    const float* __restrict__ Wq, const float* __restrict__ Wc,
    const float* __restrict__ Wout,
    ushort_t* __restrict__ inpb, ushort_t* __restrict__ ctxb,
    ushort_t* __restrict__ Wqb, ushort_t* __restrict__ Wcb,
    ushort_t* __restrict__ Woutb)
{
    const int bid = blockIdx.x;
    const float* src; ushort_t* dst; int base;
    if (bid < 128)      { src = inp;  dst = inpb;  base = bid; }
    else if (bid < 640) { src = ctx;  dst = ctxb;  base = bid - 128; }
    else if (bid < 768) { src = Wq;   dst = Wqb;   base = bid - 640; }
    else if (bid < 896) { src = Wc;   dst = Wcb;   base = bid - 768; }
    else                { src = Wout; dst = Woutb; base = bid - 896; }
    const size_t off = (size_t)base * 2048 + (size_t)threadIdx.x * 8;
    const float4* s = (const float4*)(src + off);
    float4 a = s[0], b = s[1];
    int4 r;
    r.x = bf2x(a.x, a.y); r.y = bf2x(a.z, a.w);
    r.z = bf2x(b.x, b.y); r.w = bf2x(b.z, b.w);
    *(int4*)(dst + off) = r;
}

// ---------------------------------------------------------------------------
// K1: fused front (640 GEMM blocks), all operands bf16
// [0,64)    Ew = exp(2*(inp@Wq^T + bq))
// [64,320)  Eu = exp(2*(ctx@Wc^T))
// [320,576) GT[b][n,s] = sum_d WL[n,d]*ctx[b][s,d]  (bf16)
// [576,640) Y0 = inp@WR^T + bout
// ---------------------------------------------------------------------------
__global__ __launch_bounds__(256) void fused_front(
    const ushort_t* __restrict__ inpb, const ushort_t* __restrict__ ctxb,
    const ushort_t* __restrict__ Wqb, const float* __restrict__ bq,
    const ushort_t* __restrict__ Wcb, const ushort_t* __restrict__ Woutb,
    const float* __restrict__ bout,
    float* __restrict__ Ew, float* __restrict__ Eu, float* __restrict__ Y0,
    ushort_t* __restrict__ GT)
{
    __shared__ ushort_t As[64 * 72];
    __shared__ ushort_t Ws[64 * 72];
    const int bid = blockIdx.x;

    if (bid < 64) {
        gemm_body<true, true, 1>(As, Ws, inpb, Wqb, bq, nullptr, Ew,
                                 512, 512, 512, 512, (bid & 7) * 64, (bid >> 3) * 64);
    } else if (bid < 320) {
        int i = bid - 64;
        gemm_body<true, true, 1>(As, Ws, ctxb, Wcb, nullptr, nullptr, Eu,
                                 512, 512, 512, 512, (i & 31) * 64, (i >> 5) * 64);
    } else if (bid < 576) {
        int i = bid - 320;
        int b = i >> 6, j = i & 63;
        gemm_body<true, true, 2>(As, Ws, Woutb, ctxb + (size_t)b * 262144, nullptr,
                                 nullptr, GT + (size_t)b * 262144,
                                 512, 1024, 512, 512, (j & 7) * 64, (j >> 3) * 64);
    } else {
        int i = bid - 576;
        gemm_body<true, true, 0>(As, Ws, inpb, Woutb + 512, bout, nullptr, Y0,
                                 512, 512, 1024, 512, (i & 7) * 64, (i >> 3) * 64);
    }
}

// ---------------------------------------------------------------------------
// K2: E[b,t,s] = exp(V - 2*sum_d v[d]/(1 + Ew[b,t,d]*Eu[b,s,d])),  V = sum v[d]
// Main loop: R7/R10 verbatim (k across lanes, paired rcp).
// Tail: multi-value HALVING butterfly -- 32 values/lane reduced in 32 shuffles
// (was 192): at each level a lane keeps the value-half whose index-bit matches
// its lane-bit and ships the other half. End: lane L holds S[i][j], i=(L>>3)&3,
// j=L&7 (dup on L>=32). exp applied here (maxless, R9-proven safe).
// ---------------------------------------------------------------------------
__global__ __launch_bounds__(256) void align_kernel(
    const float* __restrict__ Ew, const float* __restrict__ Eu,
    const float* __restrict__ v, float* __restrict__ out)
{
    const int lane = threadIdx.x & 63, wave = threadIdx.x >> 6;
    const int b = blockIdx.z;
    const int t0 = blockIdx.y * 16 + wave * 4;
    const int s0 = blockIdx.x * 8;

    const float* wp = Ew + (((size_t)(b * 128 + t0)) << 9);
    const float* up = Eu + (((size_t)(b * 512 + s0)) << 9);

    float acc[4][8];
    #pragma unroll
    for (int i = 0; i < 4; ++i)
        #pragma unroll
        for (int j = 0; j < 8; ++j) acc[i][j] = 0.f;
    float vsum = 0.f;

    for (int k0 = 0; k0 < 512; k0 += 128) {
        float va = v[k0 + lane];
        float vb = v[k0 + 64 + lane];
        vsum += va + vb;
        float wa[4], wb[4];
        #pragma unroll
        for (int i = 0; i < 4; ++i) {
            wa[i] = wp[i * 512 + k0 + lane];
            wb[i] = wp[i * 512 + k0 + 64 + lane];
        }
        #pragma unroll
        for (int j = 0; j < 8; ++j) {
            const float* u = up + ((size_t)j << 9) + k0 + lane;
            float ua = u[0];
            float ub = u[64];
            #pragma unroll
            for (int i = 0; i < 4; ++i) {
                float A = fmaf(wa[i], ua, 1.f);     // 1 + Ew_a*Eu_a  (>= 1)
                float B = fmaf(wb[i], ub, 1.f);     // 1 + Ew_b*Eu_b  (>= 1)
                float num = fmaf(va, B, vb * A);    // v_a*B + v_b*A
                float r = __builtin_amdgcn_rcpf(A * B);  // den safe in fp32
                acc[i][j] = fmaf(num, r, acc[i][j]);
            }
        }
    }

    float V = vsum;
    #pragma unroll
    for (int off = 32; off; off >>= 1) V += __shfl_xor(V, off, 64);

    // --- halving butterfly: value index = i*8+j (bits: j0,j1,j2,i0,i1) ---
    // level 0: lane bit0 <-> j bit0
    float x16[16];
    {
        const bool hb = lane & 1;
        #pragma unroll
        for (int i = 0; i < 4; ++i)
            #pragma unroll
            for (int m = 0; m < 4; ++m) {
                float keep = hb ? acc[i][2 * m + 1] : acc[i][2 * m];
                float send = hb ? acc[i][2 * m]     : acc[i][2 * m + 1];
                x16[i * 4 + m] = keep + __shfl_xor(send, 1, 64);
            }
    }
    // level 1: lane bit1 <-> j bit1
    float x8[8];
    {
        const bool hb = lane & 2;
        #pragma unroll
        for (int m = 0; m < 8; ++m) {
            float keep = hb ? x16[2 * m + 1] : x16[2 * m];
            float send = hb ? x16[2 * m]     : x16[2 * m + 1];
            x8[m] = keep + __shfl_xor(send, 2, 64);
        }
    }
    // level 2: lane bit2 <-> j bit2
    float x4[4];
    {
        const bool hb = lane & 4;
        #pragma unroll
        for (int m = 0; m < 4; ++m) {
            float keep = hb ? x8[2 * m + 1] : x8[2 * m];
            float send = hb ? x8[2 * m]     : x8[2 * m + 1];
            x4[m] = keep + __shfl_xor(send, 4, 64);
        }
    }
    // level 3: lane bit3 <-> i bit0
    float x2[2];
    {
        const bool hb = lane & 8;
        #pragma unroll
        for (int m = 0; m < 2; ++m) {
            float keep = hb ? x4[2 * m + 1] : x4[2 * m];
            float send = hb ? x4[2 * m]     : x4[2 * m + 1];
            x2[m] = keep + __shfl_xor(send, 8, 64);
        }
    }
    // level 4: lane bit4 <-> i bit1
    float x1;
    {
        const bool hb = lane & 16;
        float keep = hb ? x2[1] : x2[0];
        float send = hb ? x2[0] : x2[1];
        x1 = keep + __shfl_xor(send, 16, 64);
    }
    // level 5: plain add (both halves end with the full sum)
    x1 += __shfl_xor(x1, 32, 64);

    // lane L (<32; dup >=32) holds S[i][j], i=(L>>3)&3, j=L&7
    const int oi = (lane >> 3) & 3;
    const int oj = lane & 7;
    float e = __expf(fmaf(-2.f, x1, V));
    if (lane < 32) {
        out[(((size_t)(b * 128 + t0 + oi)) << 9) + s0 + oj] = e;
    }
}

// ---------------------------------------------------------------------------
// K3: maxless normalize over rows of 512. Reads E=exp(S), writes fp32 alignv
// (=E/rowsum) + bf16 P. No max pass needed (E computed exp-safely in K2).
// ---------------------------------------------------------------------------
__global__ __launch_bounds__(256) void normalize_512(
    const float* __restrict__ E, float* __restrict__ alignv,
    ushort_t* __restrict__ pbf)
{
    const int row = blockIdx.x;
    const float* p = E + ((size_t)row << 9);
    float* a = alignv + ((size_t)row << 9);
    ushort_t* q = pbf + ((size_t)row << 9);
    const int tid = threadIdx.x;
    float e0 = p[tid];
    float e1 = p[tid + 256];

    float s = e0 + e1;
    #pragma unroll
    for (int off = 32; off > 0; off >>= 1)
        s += __shfl_xor(s, off, 64);
    __shared__ float reds[4];
    const int wave = tid >> 6;
    if ((tid & 63) == 0) reds[wave] = s;
    __syncthreads();
    s = (reds[0] + reds[1]) + (reds[2] + reds[3]);
    float r = 1.0f / s;
    float p0 = e0 * r, p1 = e1 * r;
    a[tid] = p0;
    a[tid + 256] = p1;
    q[tid] = f2bf(p0);
    q[tid + 256] = f2bf(p1);
}

// ---------------------------------------------------------------------------
// K4: attn = P_bf @ GT^T + Y0. Per-batch M=128, N=512, K=512. Grid (2,8,4).
// ---------------------------------------------------------------------------
__global__ __launch_bounds__(256) void gemm_att(
    const ushort_t* __restrict__ P, const ushort_t* __restrict__ GT,
    const float* __restrict__ Y0, float* __restrict__ attn)
{
    __shared__ ushort_t As[64 * 72];
    __shared__ ushort_t Ws[64 * 72];
    const int b = blockIdx.z;
    gemm_body<true, true, 3>(As, Ws,
                             P + (size_t)b * 65536, GT + (size_t)b * 262144,
                             nullptr, Y0 + (size_t)b * 65536,
                             attn + (size_t)b * 65536,
                             512, 512, 512, 512, blockIdx.x * 64, blockIdx.y * 64);
}

// ---------------------------------------------------------------------------
extern "C" void kernel_launch(void* const* d_in, const int* in_sizes, int n_in,
                              void* d_out, int out_size, void* d_ws, size_t ws_size,
                              hipStream_t stream)
{
    const float* inp  = (const float*)d_in[0];   // (4,128,512)
    const float* ctx  = (const float*)d_in[1];   // (4,512,512)
    const float* Wq   = (const float*)d_in[2];   // (512,512)
    const float* bq   = (const float*)d_in[3];   // (512)
    const float* Wc   = (const float*)d_in[4];   // (512,512)
    const float* v    = (const float*)d_in[5];   // (512)
    const float* Wout = (const float*)d_in[6];   // (512,1024)
    const float* bout = (const float*)d_in[7];   // (512)

    float* out    = (float*)d_out;
    float* attn   = out;              // 262144 floats
    float* alignv = out + 262144;     // 262144 floats

    float* ws = (float*)d_ws;
    float* Ew   = ws;                             // 262144 f
    float* Eu   = ws + 262144;                    // 1048576 f
    float* Y0   = ws + 1310720;                   // 262144 f
    float* E    = ws + 1572864;                   // 262144 f (exp of raw scores)
    ushort_t* GT   = (ushort_t*)(ws + 1835008);   // 1048576 u16 (= 524288 f)
    ushort_t* P_bf = (ushort_t*)(ws + 2359296);   // 262144 u16 (= 131072 f)
    ushort_t* inpb  = (ushort_t*)(ws + 2490368);  // 262144 u16
    ushort_t* ctxb  = (ushort_t*)(ws + 2621440);  // 1048576 u16
    ushort_t* Wqb   = (ushort_t*)(ws + 3145728);  // 262144 u16
    ushort_t* Wcb   = (ushort_t*)(ws + 3276800);  // 262144 u16
    ushort_t* Woutb = (ushort_t*)(ws + 3407872);  // 524288 u16

    cvt_bf16<<<dim3(1152), 256, 0, stream>>>(inp, ctx, Wq, Wc, Wout,
                                             inpb, ctxb, Wqb, Wcb, Woutb);
    fused_front<<<dim3(640), 256, 0, stream>>>(inpb, ctxb, Wqb, bq, Wcb, Woutb,
                                               bout, Ew, Eu, Y0, GT);
    align_kernel<<<dim3(64, 8, 4), 256, 0, stream>>>(Ew, Eu, v, E);
    normalize_512<<<dim3(512), 256, 0, stream>>>(E, alignv, P_bf);
    gemm_att<<<dim3(2, 8, 4), 256, 0, stream>>>(P_bf, GT, Y0, attn);
}